// Round 10
// baseline (96.414 us; speedup 1.0000x reference)
//
#include <hip/hip_runtime.h>
#include <math.h>

typedef unsigned long long u64;

constexpr int T_TOTAL = 16777216;          // 2^24
constexpr int TPB     = 256;               // 4 waves per block
constexpr int SEG     = 2048;              // elements per wave segment
constexpr int NSEG    = T_TOTAL / SEG;     // 8192 segments
constexpr int NBLK    = NSEG / 4;          // 2048 blocks
constexpr int ITERS   = SEG / 128;         // 16 iterations per wave
constexpr float THRESHOLD = 0.5f;

// ---------------- pass 1: masks + intra-segment prefix bases ----------------
// Reads ONLY on/off (128 MB). Emits per-(seg,iter): 4 ballot words
// (pos_e,neg_e,pos_o,neg_o) + the net-prefix base before that iter, plus
// per-segment sums. All convergent ops (__ballot) are confined here.
#define MPROC(a, c)                                                           \
    {                                                                         \
        u64 pe_ = __ballot((a).x > (c).x);                                    \
        u64 ne_ = __ballot((c).x > (a).x);                                    \
        u64 po_ = __ballot((a).y > (c).y);                                    \
        u64 no_ = __ballot((c).y > (a).y);                                    \
        if (lane == 0) ibases[rec] = ssum;                                    \
        u64 v = pe_;                                                          \
        v = (lane == 1) ? ne_ : v;                                            \
        v = (lane == 2) ? po_ : v;                                            \
        v = (lane == 3) ? no_ : v;                                            \
        if (lane < 4) ballots[(size_t)rec * 4 + lane] = v;                    \
        ssum += __popcll(pe_) - __popcll(ne_) + __popcll(po_) - __popcll(no_);\
        rec++;                                                                \
    }

__global__ void __launch_bounds__(TPB)
k_masks(const int2* __restrict__ on2, const int2* __restrict__ off2,
        u64* __restrict__ ballots, int* __restrict__ ibases,
        int* __restrict__ segsums) {
    const int lane = threadIdx.x & 63;
    const int wid  = threadIdx.x >> 6;
    const int seg  = blockIdx.x * 4 + wid;
    const int base = seg * (SEG / 2);          // int2 index
    int ssum = 0;
    int rec  = seg * ITERS;
    #pragma unroll
    for (int g = 0; g < ITERS / 4; ++g) {
        const int i0 = base + g * 256 + lane;
        // 8 independent loads, no convergent ops in between
        int2 a0 = on2[i0];        int2 a1 = on2[i0 + 64];
        int2 a2 = on2[i0 + 128];  int2 a3 = on2[i0 + 192];
        int2 c0 = off2[i0];       int2 c1 = off2[i0 + 64];
        int2 c2 = off2[i0 + 128]; int2 c3 = off2[i0 + 192];
        MPROC(a0, c0);
        MPROC(a1, c1);
        MPROC(a2, c2);
        MPROC(a3, c3);
    }
    if (lane == 0) segsums[seg] = ssum;
}

// ---------------- pass 2: scan of segment sums ----------------
__global__ void __launch_bounds__(TPB)
k_scan(int* __restrict__ segsums) {
    __shared__ int wsum[4];
    const int lane = threadIdx.x & 63;
    const int wid  = threadIdx.x >> 6;
    int vals[NSEG / TPB];
    const int base = threadIdx.x * (NSEG / TPB);
    int s = 0;
    #pragma unroll
    for (int i = 0; i < NSEG / TPB; i++) { vals[i] = segsums[base + i]; s += vals[i]; }
    int x = s;
    #pragma unroll
    for (int d = 1; d < 64; d <<= 1) {
        int y = __shfl_up(x, d);
        if (lane >= d) x += y;
    }
    if (lane == 63) wsum[wid] = x;
    __syncthreads();
    int wbase = 0;
    #pragma unroll
    for (int w = 0; w < 3; w++) if (w < wid) wbase += wsum[w];
    int ex = wbase + (x - s);
    #pragma unroll
    for (int i = 0; i < NSEG / TPB; i++) { int v = vals[i]; segsums[base + i] = ex; ex += v; }
}

// ---------------- pass 3: u/e streaming count ----------------
// No __ballot, no serial chain: every iteration independent. Masks and
// prefix bases are wave-broadcast loads from the 4.5 MB L2-hot buffer.
__global__ void __launch_bounds__(TPB)
k_count2(const float4* __restrict__ u4, const float4* __restrict__ e4,
         const ulonglong2* __restrict__ bb, const int* __restrict__ ibases,
         const int* __restrict__ segpre, int2* __restrict__ partials) {
    const int lane = threadIdx.x & 63;
    const int wid  = threadIdx.x >> 6;
    const int seg  = blockIdx.x * 4 + wid;
    const int base = seg * (SEG / 2);          // float4 index
    const u64 le = (~0ull) >> (63 - lane);     // lanes 0..i
    const u64 lt = le >> 1;                    // lanes 0..i-1

    const int sp = segpre[seg];
    const ulonglong2* mybb = bb + (size_t)seg * ITERS * 2;
    const int* myib = ibases + seg * ITERS;

    int cover = 0, cact = 0;
    #pragma unroll 4
    for (int it = 0; it < ITERS; ++it) {
        const int idx = base + it * 64 + lane;
        float4 uv = u4[idx];
        float4 ev = e4[idx];
        ulonglong2 w01 = mybb[2 * it];         // pos_e, neg_e
        ulonglong2 w23 = mybb[2 * it + 1];     // pos_o, neg_o
        const int bp = sp + myib[it];
        const int de = __popcll(w01.x & le) - __popcll(w01.y & le);
        const int pe = bp + de + __popcll(w23.x & lt) - __popcll(w23.y & lt);
        const int po = bp + de + __popcll(w23.x & le) - __popcll(w23.y & le);
        const int a0 = pe > 0, a1 = po > 0;
        cact += a0 + a1;
        if (a0 && fabsf(ev.x - uv.x) > THRESHOLD) cover++;   // col0 of elem 2i
        if (a1 && fabsf(ev.z - uv.z) > THRESHOLD) cover++;   // col0 of elem 2i+1
    }

    #pragma unroll
    for (int d = 32; d > 0; d >>= 1) {
        cover += __shfl_xor(cover, d);
        cact  += __shfl_xor(cact, d);
    }
    __shared__ int sc[4], sa[4];
    if (lane == 0) { sc[wid] = cover; sa[wid] = cact; }
    __syncthreads();
    if (threadIdx.x == 0)
        partials[blockIdx.x] = make_int2(sc[0] + sc[1] + sc[2] + sc[3],
                                         sa[0] + sa[1] + sa[2] + sa[3]);
}

// ---------------- fallback path (round-9 proven) ----------------
__global__ void __launch_bounds__(TPB)
k_segsums(const int2* __restrict__ on2, const int2* __restrict__ off2,
          int* __restrict__ segsums) {
    const int lane = threadIdx.x & 63;
    const int wid  = threadIdx.x >> 6;
    const int seg  = blockIdx.x * 4 + wid;
    const int base = seg * (SEG / 2);
    int s = 0;
    #pragma unroll
    for (int g = 0; g < ITERS / 4; ++g) {
        const int i0 = base + g * 256 + lane;
        int2 a0 = on2[i0];        int2 a1 = on2[i0 + 64];
        int2 a2 = on2[i0 + 128];  int2 a3 = on2[i0 + 192];
        int2 c0 = off2[i0];       int2 c1 = off2[i0 + 64];
        int2 c2 = off2[i0 + 128]; int2 c3 = off2[i0 + 192];
        s += (a0.x + a0.y - c0.x - c0.y) + (a1.x + a1.y - c1.x - c1.y)
           + (a2.x + a2.y - c2.x - c2.y) + (a3.x + a3.y - c3.x - c3.y);
    }
    #pragma unroll
    for (int d = 32; d > 0; d >>= 1) s += __shfl_xor(s, d);
    if (lane == 0) segsums[seg] = s;
}

#define PROC(a, c, uv, ev)                                                    \
    {                                                                         \
        u64 be_on  = __ballot((a).x != 0);                                    \
        u64 bo_on  = __ballot((a).y != 0);                                    \
        u64 be_off = __ballot((c).x != 0);                                    \
        u64 bo_off = __ballot((c).y != 0);                                    \
        const int de = __popcll(be_on & le) - __popcll(be_off & le);          \
        const int pe = basep + de + __popcll(bo_on & lt) - __popcll(bo_off & lt); \
        const int po = basep + de + __popcll(bo_on & le) - __popcll(bo_off & le); \
        basep += __popcll(be_on) - __popcll(be_off)                           \
               + __popcll(bo_on) - __popcll(bo_off);                          \
        const int a0 = pe > 0, a1 = po > 0;                                   \
        cact += a0 + a1;                                                      \
        if (a0 && fabsf((ev).x - (uv).x) > THRESHOLD) cover++;                \
        if (a1 && fabsf((ev).z - (uv).z) > THRESHOLD) cover++;                \
    }

__global__ void __launch_bounds__(TPB)
k_count(const int2* __restrict__ on2, const int2* __restrict__ off2,
        const float4* __restrict__ u4, const float4* __restrict__ e4,
        const int* __restrict__ segpre, int2* __restrict__ partials) {
    const int lane = threadIdx.x & 63;
    const int wid  = threadIdx.x >> 6;
    const int seg  = blockIdx.x * 4 + wid;
    const int base = seg * (SEG / 2);
    const u64 le = (~0ull) >> (63 - lane);
    const u64 lt = le >> 1;
    int basep = segpre[seg];
    int cover = 0, cact = 0;
    #pragma unroll
    for (int g = 0; g < ITERS / 4; ++g) {
        const int i0 = base + g * 256 + lane;
        int2   a0 = on2[i0];        int2   a1 = on2[i0 + 64];
        int2   a2 = on2[i0 + 128];  int2   a3 = on2[i0 + 192];
        int2   c0 = off2[i0];       int2   c1 = off2[i0 + 64];
        int2   c2 = off2[i0 + 128]; int2   c3 = off2[i0 + 192];
        float4 u0 = u4[i0];         float4 u1 = u4[i0 + 64];
        float4 u2 = u4[i0 + 128];   float4 u3 = u4[i0 + 192];
        float4 e0 = e4[i0];         float4 e1 = e4[i0 + 64];
        float4 e2 = e4[i0 + 128];   float4 e3 = e4[i0 + 192];
        PROC(a0, c0, u0, e0);
        PROC(a1, c1, u1, e1);
        PROC(a2, c2, u2, e2);
        PROC(a3, c3, u3, e3);
    }
    #pragma unroll
    for (int d = 32; d > 0; d >>= 1) {
        cover += __shfl_xor(cover, d);
        cact  += __shfl_xor(cact, d);
    }
    __shared__ int sc[4], sa[4];
    if (lane == 0) { sc[wid] = cover; sa[wid] = cact; }
    __syncthreads();
    if (threadIdx.x == 0)
        partials[blockIdx.x] = make_int2(sc[0] + sc[1] + sc[2] + sc[3],
                                         sa[0] + sa[1] + sa[2] + sa[3]);
}

// ---------------- final reduce ----------------
__global__ void __launch_bounds__(TPB)
k_final(const int2* __restrict__ partials, float* __restrict__ out) {
    const int lane = threadIdx.x & 63;
    const int wid  = threadIdx.x >> 6;
    int c = 0, a = 0;
    for (int i = threadIdx.x; i < NBLK; i += TPB) {
        int2 p = partials[i];
        c += p.x; a += p.y;
    }
    #pragma unroll
    for (int d = 32; d > 0; d >>= 1) {
        c += __shfl_xor(c, d);
        a += __shfl_xor(a, d);
    }
    __shared__ int sc[4], sa[4];
    if (lane == 0) { sc[wid] = c; sa[wid] = a; }
    __syncthreads();
    if (threadIdx.x == 0) {
        float ctot = (float)(sc[0] + sc[1] + sc[2] + sc[3]);
        float atot = (float)(sa[0] + sa[1] + sa[2] + sa[3]);
        out[0] = ctot / atot;
    }
}

extern "C" void kernel_launch(void* const* d_in, const int* in_sizes, int n_in,
                              void* d_out, int out_size, void* d_ws, size_t ws_size,
                              hipStream_t stream) {
    const float* u   = (const float*)d_in[0];
    const float* e   = (const float*)d_in[1];
    const int*   on  = (const int*)d_in[2];
    const int*   off = (const int*)d_in[3];

    int*  segsums  = (int*)d_ws;                          // 32 KB
    int2* partials = (int2*)(segsums + NSEG);             // 16 KB
    int*  ibases   = (int*)((char*)d_ws + 48 * 1024);     // 512 KB
    u64*  ballots  = (u64*)((char*)d_ws + 560 * 1024);    // 4 MB

    const size_t need = 560 * 1024 + (size_t)NSEG * ITERS * 4 * sizeof(u64);

    if (ws_size >= need) {
        k_masks<<<NBLK, TPB, 0, stream>>>((const int2*)on, (const int2*)off,
                                          ballots, ibases, segsums);
        k_scan<<<1, TPB, 0, stream>>>(segsums);
        k_count2<<<NBLK, TPB, 0, stream>>>((const float4*)u, (const float4*)e,
                                           (const ulonglong2*)ballots, ibases,
                                           segsums, partials);
    } else {
        k_segsums<<<NBLK, TPB, 0, stream>>>((const int2*)on, (const int2*)off, segsums);
        k_scan<<<1, TPB, 0, stream>>>(segsums);
        k_count<<<NBLK, TPB, 0, stream>>>((const int2*)on, (const int2*)off,
                                          (const float4*)u, (const float4*)e,
                                          segsums, partials);
    }
    k_final<<<1, TPB, 0, stream>>>(partials, (float*)d_out);
}

// Round 11
// 91.810 us; speedup vs baseline: 1.0502x; 1.0502x over previous
//
#include <hip/hip_runtime.h>
#include <math.h>

typedef unsigned long long u64;

constexpr int T_TOTAL = 16777216;          // 2^24
constexpr int TPB     = 256;               // 4 waves per block
constexpr int SEG     = 2048;              // elements per wave segment
constexpr int NSEG    = T_TOTAL / SEG;     // 8192 segments
constexpr int NBLK    = NSEG / 4;          // 2048 blocks
constexpr int ITERS   = SEG / 128;         // 16 iterations per wave
constexpr float THRESHOLD = 0.5f;

// Pass 1: per-segment net sums (L3-hot, ~5 us — unchanged from r9)
__global__ void __launch_bounds__(TPB)
k_segsums(const int2* __restrict__ on2, const int2* __restrict__ off2,
          int* __restrict__ segsums) {
    const int lane = threadIdx.x & 63;
    const int wid  = threadIdx.x >> 6;
    const int seg  = blockIdx.x * 4 + wid;
    const int base = seg * (SEG / 2);          // int2 index
    int s = 0;
    #pragma unroll
    for (int g = 0; g < ITERS / 4; ++g) {
        const int i0 = base + g * 256 + lane;
        int2 a0 = on2[i0];        int2 a1 = on2[i0 + 64];
        int2 a2 = on2[i0 + 128];  int2 a3 = on2[i0 + 192];
        int2 c0 = off2[i0];       int2 c1 = off2[i0 + 64];
        int2 c2 = off2[i0 + 128]; int2 c3 = off2[i0 + 192];
        s += (a0.x + a0.y - c0.x - c0.y) + (a1.x + a1.y - c1.x - c1.y)
           + (a2.x + a2.y - c2.x - c2.y) + (a3.x + a3.y - c3.x - c3.y);
    }
    #pragma unroll
    for (int d = 32; d > 0; d >>= 1) s += __shfl_xor(s, d);
    if (lane == 0) segsums[seg] = s;
}

// Pass 2: exclusive scan of NSEG segment sums (single block, 32/thread)
__global__ void __launch_bounds__(TPB)
k_scan(int* __restrict__ segsums) {
    __shared__ int wsum[4];
    const int lane = threadIdx.x & 63;
    const int wid  = threadIdx.x >> 6;
    int vals[NSEG / TPB];
    const int base = threadIdx.x * (NSEG / TPB);
    int s = 0;
    #pragma unroll
    for (int i = 0; i < NSEG / TPB; i++) { vals[i] = segsums[base + i]; s += vals[i]; }
    int x = s;
    #pragma unroll
    for (int d = 1; d < 64; d <<= 1) {
        int y = __shfl_up(x, d);
        if (lane >= d) x += y;
    }
    if (lane == 63) wsum[wid] = x;
    __syncthreads();
    int wbase = 0;
    #pragma unroll
    for (int w = 0; w < 3; w++) if (w < wid) wbase += wsum[w];
    int ex = wbase + (x - s);
    #pragma unroll
    for (int i = 0; i < NSEG / TPB; i++) { int v = vals[i]; segsums[base + i] = ex; ex += v; }
}

// Per-128-element ballot/popc process step (identical math to r6/r9,
// absmax 0.0 validated)
#define PROC(a, c, uv, ev)                                                    \
    {                                                                         \
        u64 be_on  = __ballot((a).x != 0);                                    \
        u64 bo_on  = __ballot((a).y != 0);                                    \
        u64 be_off = __ballot((c).x != 0);                                    \
        u64 bo_off = __ballot((c).y != 0);                                    \
        const int de = __popcll(be_on & le) - __popcll(be_off & le);          \
        const int pe = basep + de + __popcll(bo_on & lt) - __popcll(bo_off & lt); \
        const int po = basep + de + __popcll(bo_on & le) - __popcll(bo_off & le); \
        basep += __popcll(be_on) - __popcll(be_off)                           \
               + __popcll(bo_on) - __popcll(bo_off);                          \
        const int a0 = pe > 0, a1 = po > 0;                                   \
        cact += a0 + a1;                                                      \
        if (a0 && fabsf((ev).x - (uv).x) > THRESHOLD) cover++;                \
        if (a1 && fabsf((ev).z - (uv).z) > THRESHOLD) cover++;                \
    }

// Pass 3: 8-deep load batches (32 interleaved loads in flight), register
// budget unlocked via __launch_bounds__(TPB, 1).
__global__ void __launch_bounds__(TPB, 1)
k_count(const int2* __restrict__ on2, const int2* __restrict__ off2,
        const float4* __restrict__ u4, const float4* __restrict__ e4,
        const int* __restrict__ segpre, int2* __restrict__ partials) {
    const int lane = threadIdx.x & 63;
    const int wid  = threadIdx.x >> 6;
    const int seg  = blockIdx.x * 4 + wid;
    const int base = seg * (SEG / 2);          // int2 index == float4 index
    const u64 le = (~0ull) >> (63 - lane);     // lanes 0..i
    const u64 lt = le >> 1;                    // lanes 0..i-1

    int basep = segpre[seg];
    int cover = 0, cact = 0;

    #pragma unroll
    for (int g = 0; g < ITERS / 8; ++g) {
        const int i0 = base + g * 512 + lane;
        // ---- 32 independent loads, issued in per-iteration quads ----
        int2 a0 = on2[i0      ]; int2 c0 = off2[i0      ]; float4 u0 = u4[i0      ]; float4 e0 = e4[i0      ];
        int2 a1 = on2[i0 +  64]; int2 c1 = off2[i0 +  64]; float4 u1 = u4[i0 +  64]; float4 e1 = e4[i0 +  64];
        int2 a2 = on2[i0 + 128]; int2 c2 = off2[i0 + 128]; float4 u2 = u4[i0 + 128]; float4 e2 = e4[i0 + 128];
        int2 a3 = on2[i0 + 192]; int2 c3 = off2[i0 + 192]; float4 u3 = u4[i0 + 192]; float4 e3 = e4[i0 + 192];
        int2 a4 = on2[i0 + 256]; int2 c4 = off2[i0 + 256]; float4 u4v = u4[i0 + 256]; float4 e4v = e4[i0 + 256];
        int2 a5 = on2[i0 + 320]; int2 c5 = off2[i0 + 320]; float4 u5 = u4[i0 + 320]; float4 e5 = e4[i0 + 320];
        int2 a6 = on2[i0 + 384]; int2 c6 = off2[i0 + 384]; float4 u6 = u4[i0 + 384]; float4 e6 = e4[i0 + 384];
        int2 a7 = on2[i0 + 448]; int2 c7 = off2[i0 + 448]; float4 u7 = u4[i0 + 448]; float4 e7 = e4[i0 + 448];
        // ---- process 8 sub-iterations (ordered: prefix chain) ----
        PROC(a0, c0, u0, e0);
        PROC(a1, c1, u1, e1);
        PROC(a2, c2, u2, e2);
        PROC(a3, c3, u3, e3);
        PROC(a4, c4, u4v, e4v);
        PROC(a5, c5, u5, e5);
        PROC(a6, c6, u6, e6);
        PROC(a7, c7, u7, e7);
    }

    #pragma unroll
    for (int d = 32; d > 0; d >>= 1) {
        cover += __shfl_xor(cover, d);
        cact  += __shfl_xor(cact, d);
    }
    __shared__ int sc[4], sa[4];
    if (lane == 0) { sc[wid] = cover; sa[wid] = cact; }
    __syncthreads();
    if (threadIdx.x == 0)
        partials[blockIdx.x] = make_int2(sc[0] + sc[1] + sc[2] + sc[3],
                                         sa[0] + sa[1] + sa[2] + sa[3]);
}

// Pass 4: reduce block partials, divide
__global__ void __launch_bounds__(TPB)
k_final(const int2* __restrict__ partials, float* __restrict__ out) {
    const int lane = threadIdx.x & 63;
    const int wid  = threadIdx.x >> 6;
    int c = 0, a = 0;
    for (int i = threadIdx.x; i < NBLK; i += TPB) {
        int2 p = partials[i];
        c += p.x; a += p.y;
    }
    #pragma unroll
    for (int d = 32; d > 0; d >>= 1) {
        c += __shfl_xor(c, d);
        a += __shfl_xor(a, d);
    }
    __shared__ int sc[4], sa[4];
    if (lane == 0) { sc[wid] = c; sa[wid] = a; }
    __syncthreads();
    if (threadIdx.x == 0) {
        float ctot = (float)(sc[0] + sc[1] + sc[2] + sc[3]);
        float atot = (float)(sa[0] + sa[1] + sa[2] + sa[3]);
        out[0] = ctot / atot;
    }
}

extern "C" void kernel_launch(void* const* d_in, const int* in_sizes, int n_in,
                              void* d_out, int out_size, void* d_ws, size_t ws_size,
                              hipStream_t stream) {
    const float* u   = (const float*)d_in[0];
    const float* e   = (const float*)d_in[1];
    const int*   on  = (const int*)d_in[2];
    const int*   off = (const int*)d_in[3];

    int*  segsums  = (int*)d_ws;                 // NSEG ints (32 KB)
    int2* partials = (int2*)(segsums + NSEG);    // NBLK int2 (16 KB)

    k_segsums<<<NBLK, TPB, 0, stream>>>((const int2*)on, (const int2*)off, segsums);
    k_scan<<<1, TPB, 0, stream>>>(segsums);
    k_count<<<NBLK, TPB, 0, stream>>>((const int2*)on, (const int2*)off,
                                      (const float4*)u, (const float4*)e,
                                      segsums, partials);
    k_final<<<1, TPB, 0, stream>>>(partials, (float*)d_out);
}

// Round 12
// 91.516 us; speedup vs baseline: 1.0535x; 1.0032x over previous
//
#include <hip/hip_runtime.h>
#include <math.h>

typedef unsigned long long u64;
typedef int   vi2 __attribute__((ext_vector_type(2)));
typedef float vf4 __attribute__((ext_vector_type(4)));

constexpr int T_TOTAL = 16777216;          // 2^24
constexpr int TPB     = 256;               // 4 waves per block
constexpr int SEG     = 2048;              // elements per wave segment
constexpr int NSEG    = T_TOTAL / SEG;     // 8192 segments
constexpr int NBLK    = NSEG / 4;          // 2048 blocks
constexpr int ITERS   = SEG / 128;         // 16 iterations per wave
constexpr float THRESHOLD = 0.5f;

// Pass 1: per-segment net sums (L3-hot, ~5 us — unchanged from r9)
__global__ void __launch_bounds__(TPB)
k_segsums(const int2* __restrict__ on2, const int2* __restrict__ off2,
          int* __restrict__ segsums) {
    const int lane = threadIdx.x & 63;
    const int wid  = threadIdx.x >> 6;
    const int seg  = blockIdx.x * 4 + wid;
    const int base = seg * (SEG / 2);          // int2 index
    int s = 0;
    #pragma unroll
    for (int g = 0; g < ITERS / 4; ++g) {
        const int i0 = base + g * 256 + lane;
        int2 a0 = on2[i0];        int2 a1 = on2[i0 + 64];
        int2 a2 = on2[i0 + 128];  int2 a3 = on2[i0 + 192];
        int2 c0 = off2[i0];       int2 c1 = off2[i0 + 64];
        int2 c2 = off2[i0 + 128]; int2 c3 = off2[i0 + 192];
        s += (a0.x + a0.y - c0.x - c0.y) + (a1.x + a1.y - c1.x - c1.y)
           + (a2.x + a2.y - c2.x - c2.y) + (a3.x + a3.y - c3.x - c3.y);
    }
    #pragma unroll
    for (int d = 32; d > 0; d >>= 1) s += __shfl_xor(s, d);
    if (lane == 0) segsums[seg] = s;
}

// Pass 2: exclusive scan of NSEG segment sums (single block, 32/thread)
__global__ void __launch_bounds__(TPB)
k_scan(int* __restrict__ segsums) {
    __shared__ int wsum[4];
    const int lane = threadIdx.x & 63;
    const int wid  = threadIdx.x >> 6;
    int vals[NSEG / TPB];
    const int base = threadIdx.x * (NSEG / TPB);
    int s = 0;
    #pragma unroll
    for (int i = 0; i < NSEG / TPB; i++) { vals[i] = segsums[base + i]; s += vals[i]; }
    int x = s;
    #pragma unroll
    for (int d = 1; d < 64; d <<= 1) {
        int y = __shfl_up(x, d);
        if (lane >= d) x += y;
    }
    if (lane == 63) wsum[wid] = x;
    __syncthreads();
    int wbase = 0;
    #pragma unroll
    for (int w = 0; w < 3; w++) if (w < wid) wbase += wsum[w];
    int ex = wbase + (x - s);
    #pragma unroll
    for (int i = 0; i < NSEG / TPB; i++) { int v = vals[i]; segsums[base + i] = ex; ex += v; }
}

// Inline-asm load bursts: asm volatile preserves issue order, so 16 loads go
// out back-to-back (16 outstanding per wave) — the HIP scheduler cannot sink
// them to their uses (which it did in r8-r11, capping MLP at ~5 loads/wave).
#define G_LOAD2(dst, voff, base, OFFS)                                        \
    asm volatile("global_load_dwordx2 %0, %1, %2 offset:" OFFS                \
                 : "=v"(dst) : "v"(voff), "s"(base))
#define G_LOAD4(dst, voff, base, OFFS)                                        \
    asm volatile("global_load_dwordx4 %0, %1, %2 offset:" OFFS                \
                 : "=v"(dst) : "v"(voff), "s"(base))

// Per-128-element ballot/popc process step (identical math to r6-r11,
// absmax 0.0 validated)
#define PROC(a, c, uv, ev)                                                    \
    {                                                                         \
        u64 be_on  = __ballot((a).x != 0);                                    \
        u64 bo_on  = __ballot((a).y != 0);                                    \
        u64 be_off = __ballot((c).x != 0);                                    \
        u64 bo_off = __ballot((c).y != 0);                                    \
        const int de = __popcll(be_on & le) - __popcll(be_off & le);          \
        const int pe = basep + de + __popcll(bo_on & lt) - __popcll(bo_off & lt); \
        const int po = basep + de + __popcll(bo_on & le) - __popcll(bo_off & le); \
        basep += __popcll(be_on) - __popcll(be_off)                           \
               + __popcll(bo_on) - __popcll(bo_off);                          \
        const int a0 = pe > 0, a1 = po > 0;                                   \
        cact += a0 + a1;                                                      \
        if (a0 && fabsf((ev).x - (uv).x) > THRESHOLD) cover++;                \
        if (a1 && fabsf((ev).z - (uv).z) > THRESHOLD) cover++;                \
    }

// Pass 3: per 512-element group, burst 16 asm loads -> vmcnt(0) ->
// sched_barrier (rule #18: reg-only consumers are NOT ordered by the
// waitcnt's memory clobber) -> 4 PROC steps.
__global__ void __launch_bounds__(TPB)
k_count(const int* __restrict__ on_, const int* __restrict__ off_,
        const float* __restrict__ u_, const float* __restrict__ e_,
        const int* __restrict__ segpre, int2* __restrict__ partials) {
    const int lane = threadIdx.x & 63;
    const int wid  = threadIdx.x >> 6;
    const int seg  = blockIdx.x * 4 + wid;
    const int base = seg * (SEG / 2);          // int2 index == float4 index
    const u64 le = (~0ull) >> (63 - lane);     // lanes 0..i
    const u64 lt = le >> 1;                    // lanes 0..i-1

    int basep = segpre[seg];
    int cover = 0, cact = 0;

    #pragma unroll
    for (int g = 0; g < ITERS / 4; ++g) {
        const unsigned o8  = (unsigned)(base + g * 256 + lane) * 8u;   // int2 bytes
        const unsigned o16 = o8 * 2u;                                  // float4 bytes
        vi2 a0, a1, a2, a3, c0, c1, c2, c3;
        vf4 u0, u1, u2, u3, e0, e1, e2, e3;
        // ---- 16 loads issued back-to-back, program order preserved ----
        G_LOAD2(a0, o8,  on_,  "0");
        G_LOAD2(a1, o8,  on_,  "512");
        G_LOAD2(a2, o8,  on_,  "1024");
        G_LOAD2(a3, o8,  on_,  "1536");
        G_LOAD2(c0, o8,  off_, "0");
        G_LOAD2(c1, o8,  off_, "512");
        G_LOAD2(c2, o8,  off_, "1024");
        G_LOAD2(c3, o8,  off_, "1536");
        G_LOAD4(u0, o16, u_,   "0");
        G_LOAD4(u1, o16, u_,   "1024");
        G_LOAD4(u2, o16, u_,   "2048");
        G_LOAD4(u3, o16, u_,   "3072");
        G_LOAD4(e0, o16, e_,   "0");
        G_LOAD4(e1, o16, e_,   "1024");
        G_LOAD4(e2, o16, e_,   "2048");
        G_LOAD4(e3, o16, e_,   "3072");
        asm volatile("s_waitcnt vmcnt(0)" ::: "memory");
        __builtin_amdgcn_sched_barrier(0);
        // ---- process 4 sub-iterations (prefix chain is serial by design) ----
        PROC(a0, c0, u0, e0);
        PROC(a1, c1, u1, e1);
        PROC(a2, c2, u2, e2);
        PROC(a3, c3, u3, e3);
    }

    #pragma unroll
    for (int d = 32; d > 0; d >>= 1) {
        cover += __shfl_xor(cover, d);
        cact  += __shfl_xor(cact, d);
    }
    __shared__ int sc[4], sa[4];
    if (lane == 0) { sc[wid] = cover; sa[wid] = cact; }
    __syncthreads();
    if (threadIdx.x == 0)
        partials[blockIdx.x] = make_int2(sc[0] + sc[1] + sc[2] + sc[3],
                                         sa[0] + sa[1] + sa[2] + sa[3]);
}

// Pass 4: reduce block partials, divide
__global__ void __launch_bounds__(TPB)
k_final(const int2* __restrict__ partials, float* __restrict__ out) {
    const int lane = threadIdx.x & 63;
    const int wid  = threadIdx.x >> 6;
    int c = 0, a = 0;
    for (int i = threadIdx.x; i < NBLK; i += TPB) {
        int2 p = partials[i];
        c += p.x; a += p.y;
    }
    #pragma unroll
    for (int d = 32; d > 0; d >>= 1) {
        c += __shfl_xor(c, d);
        a += __shfl_xor(a, d);
    }
    __shared__ int sc[4], sa[4];
    if (lane == 0) { sc[wid] = c; sa[wid] = a; }
    __syncthreads();
    if (threadIdx.x == 0) {
        float ctot = (float)(sc[0] + sc[1] + sc[2] + sc[3]);
        float atot = (float)(sa[0] + sa[1] + sa[2] + sa[3]);
        out[0] = ctot / atot;
    }
}

extern "C" void kernel_launch(void* const* d_in, const int* in_sizes, int n_in,
                              void* d_out, int out_size, void* d_ws, size_t ws_size,
                              hipStream_t stream) {
    const float* u   = (const float*)d_in[0];
    const float* e   = (const float*)d_in[1];
    const int*   on  = (const int*)d_in[2];
    const int*   off = (const int*)d_in[3];

    int*  segsums  = (int*)d_ws;                 // NSEG ints (32 KB)
    int2* partials = (int2*)(segsums + NSEG);    // NBLK int2 (16 KB)

    k_segsums<<<NBLK, TPB, 0, stream>>>((const int2*)on, (const int2*)off, segsums);
    k_scan<<<1, TPB, 0, stream>>>(segsums);
    k_count<<<NBLK, TPB, 0, stream>>>(on, off, u, e, segsums, partials);
    k_final<<<1, TPB, 0, stream>>>(partials, (float*)d_out);
}

// Round 14
// 89.678 us; speedup vs baseline: 1.0751x; 1.0205x over previous
//
#include <hip/hip_runtime.h>
#include <math.h>

typedef unsigned long long u64;
typedef float vf4 __attribute__((ext_vector_type(4)));   // clang vector: ok for nontemporal builtin

constexpr int T_TOTAL = 16777216;          // 2^24
constexpr int TPB     = 256;               // 4 waves per block
constexpr int SEG     = 2048;              // elements per wave segment
constexpr int NSEG    = T_TOTAL / SEG;     // 8192 segments
constexpr int NBLK    = NSEG / 4;          // 2048 blocks
constexpr int ITERS   = SEG / 128;         // 16 iterations per wave
constexpr float THRESHOLD = 0.5f;

// Pass 1: per-segment net sums (on/off L3-hot — unchanged from r9)
__global__ void __launch_bounds__(TPB)
k_segsums(const int2* __restrict__ on2, const int2* __restrict__ off2,
          int* __restrict__ segsums) {
    const int lane = threadIdx.x & 63;
    const int wid  = threadIdx.x >> 6;
    const int seg  = blockIdx.x * 4 + wid;
    const int base = seg * (SEG / 2);          // int2 index
    int s = 0;
    #pragma unroll
    for (int g = 0; g < ITERS / 4; ++g) {
        const int i0 = base + g * 256 + lane;
        int2 a0 = on2[i0];        int2 a1 = on2[i0 + 64];
        int2 a2 = on2[i0 + 128];  int2 a3 = on2[i0 + 192];
        int2 c0 = off2[i0];       int2 c1 = off2[i0 + 64];
        int2 c2 = off2[i0 + 128]; int2 c3 = off2[i0 + 192];
        s += (a0.x + a0.y - c0.x - c0.y) + (a1.x + a1.y - c1.x - c1.y)
           + (a2.x + a2.y - c2.x - c2.y) + (a3.x + a3.y - c3.x - c3.y);
    }
    #pragma unroll
    for (int d = 32; d > 0; d >>= 1) s += __shfl_xor(s, d);
    if (lane == 0) segsums[seg] = s;
}

// Pass 2: exclusive scan of NSEG segment sums (single block, 32/thread)
__global__ void __launch_bounds__(TPB)
k_scan(int* __restrict__ segsums) {
    __shared__ int wsum[4];
    const int lane = threadIdx.x & 63;
    const int wid  = threadIdx.x >> 6;
    int vals[NSEG / TPB];
    const int base = threadIdx.x * (NSEG / TPB);
    int s = 0;
    #pragma unroll
    for (int i = 0; i < NSEG / TPB; i++) { vals[i] = segsums[base + i]; s += vals[i]; }
    int x = s;
    #pragma unroll
    for (int d = 1; d < 64; d <<= 1) {
        int y = __shfl_up(x, d);
        if (lane >= d) x += y;
    }
    if (lane == 63) wsum[wid] = x;
    __syncthreads();
    int wbase = 0;
    #pragma unroll
    for (int w = 0; w < 3; w++) if (w < wid) wbase += wsum[w];
    int ex = wbase + (x - s);
    #pragma unroll
    for (int i = 0; i < NSEG / TPB; i++) { int v = vals[i]; segsums[base + i] = ex; ex += v; }
}

// Per-128-element ballot/popc process step (identical math to r6-r12,
// absmax 0.0 validated). uv/ev are vf4: [0]=col0 of elem 2i, [2]=col0 of 2i+1.
#define PROC(a, c, uv, ev)                                                    \
    {                                                                         \
        u64 be_on  = __ballot((a).x != 0);                                    \
        u64 bo_on  = __ballot((a).y != 0);                                    \
        u64 be_off = __ballot((c).x != 0);                                    \
        u64 bo_off = __ballot((c).y != 0);                                    \
        const int de = __popcll(be_on & le) - __popcll(be_off & le);          \
        const int pe = basep + de + __popcll(bo_on & lt) - __popcll(bo_off & lt); \
        const int po = basep + de + __popcll(bo_on & le) - __popcll(bo_off & le); \
        basep += __popcll(be_on) - __popcll(be_off)                           \
               + __popcll(bo_on) - __popcll(bo_off);                          \
        const int a0 = pe > 0, a1 = po > 0;                                   \
        cact += a0 + a1;                                                      \
        if (a0 && fabsf((ev)[0] - (uv)[0]) > THRESHOLD) cover++;              \
        if (a1 && fabsf((ev)[2] - (uv)[2]) > THRESHOLD) cover++;              \
    }

// Pass 3: r9 structure (best measured), but u/e loads are NON-TEMPORAL:
// u/e (256 MB, zero reuse) no longer thrash L3, so on/off (128 MB) stays
// L3-resident and the scan-side loads see short latency.
__global__ void __launch_bounds__(TPB)
k_count(const int2* __restrict__ on2, const int2* __restrict__ off2,
        const vf4* __restrict__ u4, const vf4* __restrict__ e4,
        const int* __restrict__ segpre, int2* __restrict__ partials) {
    const int lane = threadIdx.x & 63;
    const int wid  = threadIdx.x >> 6;
    const int seg  = blockIdx.x * 4 + wid;
    const int base = seg * (SEG / 2);          // int2 index == float4 index
    const u64 le = (~0ull) >> (63 - lane);     // lanes 0..i
    const u64 lt = le >> 1;                    // lanes 0..i-1

    int basep = segpre[seg];
    int cover = 0, cact = 0;

    #pragma unroll
    for (int g = 0; g < ITERS / 4; ++g) {
        const int i0 = base + g * 256 + lane;
        // ---- 16 loads batched; u/e marked non-temporal ----
        int2 a0 = on2[i0];        int2 a1 = on2[i0 + 64];
        int2 a2 = on2[i0 + 128];  int2 a3 = on2[i0 + 192];
        int2 c0 = off2[i0];       int2 c1 = off2[i0 + 64];
        int2 c2 = off2[i0 + 128]; int2 c3 = off2[i0 + 192];
        vf4 u0 = __builtin_nontemporal_load(u4 + i0);
        vf4 u1 = __builtin_nontemporal_load(u4 + i0 + 64);
        vf4 u2 = __builtin_nontemporal_load(u4 + i0 + 128);
        vf4 u3 = __builtin_nontemporal_load(u4 + i0 + 192);
        vf4 e0 = __builtin_nontemporal_load(e4 + i0);
        vf4 e1 = __builtin_nontemporal_load(e4 + i0 + 64);
        vf4 e2 = __builtin_nontemporal_load(e4 + i0 + 128);
        vf4 e3 = __builtin_nontemporal_load(e4 + i0 + 192);
        // ---- process 4 sub-iterations ----
        PROC(a0, c0, u0, e0);
        PROC(a1, c1, u1, e1);
        PROC(a2, c2, u2, e2);
        PROC(a3, c3, u3, e3);
    }

    #pragma unroll
    for (int d = 32; d > 0; d >>= 1) {
        cover += __shfl_xor(cover, d);
        cact  += __shfl_xor(cact, d);
    }
    __shared__ int sc[4], sa[4];
    if (lane == 0) { sc[wid] = cover; sa[wid] = cact; }
    __syncthreads();
    if (threadIdx.x == 0)
        partials[blockIdx.x] = make_int2(sc[0] + sc[1] + sc[2] + sc[3],
                                         sa[0] + sa[1] + sa[2] + sa[3]);
}

// Pass 4: reduce block partials, divide
__global__ void __launch_bounds__(TPB)
k_final(const int2* __restrict__ partials, float* __restrict__ out) {
    const int lane = threadIdx.x & 63;
    const int wid  = threadIdx.x >> 6;
    int c = 0, a = 0;
    for (int i = threadIdx.x; i < NBLK; i += TPB) {
        int2 p = partials[i];
        c += p.x; a += p.y;
    }
    #pragma unroll
    for (int d = 32; d > 0; d >>= 1) {
        c += __shfl_xor(c, d);
        a += __shfl_xor(a, d);
    }
    __shared__ int sc[4], sa[4];
    if (lane == 0) { sc[wid] = c; sa[wid] = a; }
    __syncthreads();
    if (threadIdx.x == 0) {
        float ctot = (float)(sc[0] + sc[1] + sc[2] + sc[3]);
        float atot = (float)(sa[0] + sa[1] + sa[2] + sa[3]);
        out[0] = ctot / atot;
    }
}

extern "C" void kernel_launch(void* const* d_in, const int* in_sizes, int n_in,
                              void* d_out, int out_size, void* d_ws, size_t ws_size,
                              hipStream_t stream) {
    const float* u   = (const float*)d_in[0];
    const float* e   = (const float*)d_in[1];
    const int*   on  = (const int*)d_in[2];
    const int*   off = (const int*)d_in[3];

    int*  segsums  = (int*)d_ws;                 // NSEG ints (32 KB)
    int2* partials = (int2*)(segsums + NSEG);    // NBLK int2 (16 KB)

    k_segsums<<<NBLK, TPB, 0, stream>>>((const int2*)on, (const int2*)off, segsums);
    k_scan<<<1, TPB, 0, stream>>>(segsums);
    k_count<<<NBLK, TPB, 0, stream>>>((const int2*)on, (const int2*)off,
                                      (const vf4*)u, (const vf4*)e,
                                      segsums, partials);
    k_final<<<1, TPB, 0, stream>>>(partials, (float*)d_out);
}